// Round 10
// baseline (5545.073 us; speedup 1.0000x reference)
//
#include <hip/hip_runtime.h>
#include <stdint.h>

#define B_ 64
#define T_ 2048
#define H_ 256
#define S_ 64              // chunk length (timesteps)
#define C_ (T_ / S_)       // 32 chunks

typedef unsigned int u32;
typedef unsigned short u16;
typedef __attribute__((ext_vector_type(8))) short short8;
typedef __attribute__((ext_vector_type(4))) float f32x4;

// bf16 tile swizzle (verified rounds 4-9): conflict-free ds_read_b128 at
// (row=lane&15, slice=(lane>>4)*8); same formula on write and read.
#define SWZ(row, byte) (((row) * 512) + ((byte) ^ (((row) & 7) << 4)))

static __device__ __forceinline__ u32 cvtpk(float a, float b) {
  u32 d;
  asm("v_cvt_pk_bf16_f32 %0, %1, %2" : "=v"(d) : "v"(a), "v"(b));
  return d;
}
static __device__ __forceinline__ uint4 pack8(float4 a, float4 b) {
  uint4 r;
  r.x = cvtpk(a.x, a.y); r.y = cvtpk(a.z, a.w);
  r.z = cvtpk(b.x, b.y); r.w = cvtpk(b.z, b.w);
  return r;
}
static __device__ __forceinline__ short8 as8(uint4 v) {
  return __builtin_bit_cast(short8, v);
}
static __device__ __forceinline__ f32x4 mfma4(uint4 a, uint4 b, f32x4 c) {
  return __builtin_amdgcn_mfma_f32_16x16x32_bf16(as8(a), as8(b), c, 0, 0, 0);
}
// 1 - 2*rcp(e^{2x}+1); ~1ulp f32 << bf16 rounding; saturates correctly.
static __device__ __forceinline__ float fast_tanh(float x) {
  float e = __expf(2.0f * x);
  float r = __builtin_amdgcn_rcpf(e + 1.0f);
  return fmaf(-2.0f, r, 1.0f);
}

// Verified A/B fragment loader for mfma_f32_16x16x32_bf16 [m89/m91].
template <int NQ>
static __device__ __forceinline__ void load_wfrag(const float* W, int qbase, int bl,
                                                  int g, uint4 wf[NQ][8]) {
#pragma unroll
  for (int q = 0; q < NQ; ++q) {
    const float* wr = W + (size_t)((qbase + q) * 16 + bl) * H_ + g * 8;
#pragma unroll
    for (int kc = 0; kc < 8; ++kc) {
      float4 a = *(const float4*)(wr + kc * 32);
      float4 b = *(const float4*)(wr + kc * 32 + 4);
      wf[q][kc] = pack8(a, b);
    }
  }
}

// ---------------- layer-0 pre-projection over full T (verified) ----------------
__global__ __launch_bounds__(256, 2) void pre_mfma(const float* X, const float* W,
                                                   const float* bi, const float* bh,
                                                   float* P, int tpw) {
  __shared__ char sb_[2][8192];
  const int tid = threadIdx.x;
  const int lane = tid & 63, wv = tid >> 6;
  const int bl = lane & 15, g = lane >> 4;

  uint4 wf[4][8];
  load_wfrag<4>(W, wv * 4, bl, g, wf);
  float4 bias[4];
#pragma unroll
  for (int q = 0; q < 4; ++q) {
    const int j0 = (wv * 4 + q) * 16 + g * 4;
    float4 a = *(const float4*)(bi + j0);
    float4 c = *(const float4*)(bh + j0);
    bias[q].x = a.x + c.x; bias[q].y = a.y + c.y;
    bias[q].z = a.z + c.z; bias[q].w = a.w + c.w;
  }

  const size_t row0 = (size_t)blockIdx.x * tpw * 16;
  const int sr = tid >> 4, sc = (tid & 15) * 16;
  float4 s0, s1, s2, s3;
  {
    const float4* xs = (const float4*)(X + (row0 + sr) * H_ + sc);
    s0 = xs[0]; s1 = xs[1]; s2 = xs[2]; s3 = xs[3];
  }

  for (int i = 0; i < tpw; ++i) {
    char* sb = sb_[i & 1];
    *(uint4*)(sb + SWZ(sr, sc * 2)) = pack8(s0, s1);
    *(uint4*)(sb + SWZ(sr, sc * 2 + 16)) = pack8(s2, s3);
    __syncthreads();
    if (i + 1 < tpw) {
      const float4* xn = (const float4*)(X + (row0 + (i + 1) * 16 + sr) * H_ + sc);
      s0 = xn[0]; s1 = xn[1]; s2 = xn[2]; s3 = xn[3];
    }
    uint4 hf[8];
#pragma unroll
    for (int kc = 0; kc < 8; ++kc)
      hf[kc] = *(const uint4*)(sb + SWZ(bl, kc * 64 + g * 16));
    f32x4 acc[4];
#pragma unroll
    for (int q = 0; q < 4; ++q) {
      acc[q] = (f32x4){0.f, 0.f, 0.f, 0.f};
#pragma unroll
      for (int kc = 0; kc < 8; ++kc)
        acc[q] = mfma4(wf[q][kc], hf[kc], acc[q]);
    }
#pragma unroll
    for (int q = 0; q < 4; ++q) {
      const int j0 = (wv * 4 + q) * 16 + g * 4;
      float4 o;
      o.x = acc[q][0] + bias[q].x; o.y = acc[q][1] + bias[q].y;
      o.z = acc[q][2] + bias[q].z; o.w = acc[q][3] + bias[q].w;
      *(float4*)(P + (row0 + i * 16 + bl) * H_ + j0) = o;
    }
    __syncthreads();
  }
}

// ---------------- fallback standalone recurrence (round-6, verified) ----------------
__global__ __launch_bounds__(512, 1) void rec_mfma(const float* pre, const float* W,
                                                   float* out) {
  __shared__ char hb_[2][8192];
  const int tid = threadIdx.x;
  const int lane = tid & 63, wv = tid >> 6;
  const int bl = lane & 15, g = lane >> 4;
  const int b0 = blockIdx.x * 16;

  uint4 wf[2][8];
  load_wfrag<2>(W, wv * 2, bl, g, wf);
  {
    uint4 z = make_uint4(0, 0, 0, 0);
    ((uint4*)hb_[0])[tid] = z;
    ((uint4*)hb_[1])[tid] = z;
  }
  const float* prow = pre + (size_t)(b0 + bl) * T_ * H_;
  float* orow = out + (size_t)(b0 + bl) * T_ * H_;
  float4 pr0[2], pr1[2];
#pragma unroll
  for (int q = 0; q < 2; ++q) {
    const int j0 = (wv * 2 + q) * 16 + g * 4;
    pr0[q] = *(const float4*)(prow + 0 * H_ + j0);
    pr1[q] = *(const float4*)(prow + 1 * H_ + j0);
  }
  __syncthreads();

  auto step = [&](int t, float4 (&pr)[2], char* rbuf, char* wbuf) {
    uint4 hf[8];
#pragma unroll
    for (int kc = 0; kc < 8; ++kc)
      hf[kc] = *(const uint4*)(rbuf + SWZ(bl, kc * 64 + g * 16));
    f32x4 accA[2], accB[2];
#pragma unroll
    for (int q = 0; q < 2; ++q) {
      accA[q] = (f32x4){0.f, 0.f, 0.f, 0.f};
      accB[q] = (f32x4){0.f, 0.f, 0.f, 0.f};
#pragma unroll
      for (int kc = 0; kc < 4; ++kc) {
        accA[q] = mfma4(wf[q][kc], hf[kc], accA[q]);
        accB[q] = mfma4(wf[q][kc + 4], hf[kc + 4], accB[q]);
      }
    }
#pragma unroll
    for (int q = 0; q < 2; ++q) {
      const int j0 = (wv * 2 + q) * 16 + g * 4;
      const float* pq = (const float*)&pr[q];
      float v0 = fast_tanh(accA[q][0] + accB[q][0] + pq[0]);
      float v1 = fast_tanh(accA[q][1] + accB[q][1] + pq[1]);
      float v2 = fast_tanh(accA[q][2] + accB[q][2] + pq[2]);
      float v3 = fast_tanh(accA[q][3] + accB[q][3] + pq[3]);
      uint2 hw; hw.x = cvtpk(v0, v1); hw.y = cvtpk(v2, v3);
      *(uint2*)(wbuf + SWZ(bl, j0 * 2)) = hw;
      float4 o; o.x = v0; o.y = v1; o.z = v2; o.w = v3;
      *(float4*)(orow + (size_t)t * H_ + j0) = o;
      if (t + 2 < T_)
        pr[q] = *(const float4*)(prow + (size_t)(t + 2) * H_ + j0);
    }
    asm volatile("s_waitcnt lgkmcnt(0)" ::: "memory");
    __builtin_amdgcn_s_barrier();
    __builtin_amdgcn_sched_barrier(0);
  };

  for (int t = 0; t < T_; t += 2) {
    step(t, pr0, hb_[0], hb_[1]);
    step(t + 1, pr1, hb_[1], hb_[0]);
  }
}

// ---------------- 3-stage chunk pipeline, 2-group fused rec WGs ----------------
// Kernel c: blocks 0-1 rec0(chunk c, 32 batch each: 2 independent 16-batch
// groups per WG, waves 0-3 / 4-7, each wave NQ=4) -> h0 bf16 ring;
// blocks 2-5 proj1(chunk c-1): c1 = Wih1*h0 + b -> f32 into d_out[chunk c-1];
// blocks 6-7 rec1(chunk c-2, same 2-group shape): in-place on d_out.
// All cross-stage data crosses a kernel boundary -> coherent (G16);
// deterministic & graph-replay safe.
__global__ __launch_bounds__(512, 1) void chunk3_k(
    float* dout, const float* Whh0, const float* Wih1, const float* Whh1,
    const float* bih1, const float* bhh1,
    u16* ring, u16* carry0, u16* carry1, int c) {
  __shared__ __align__(16) char smem[4 * 8192];  // [grp][buf] for rec; [buf] for proj
  const int tid = threadIdx.x;
  const int lane = tid & 63, wv = tid >> 6;
  const int bl = lane & 15, g = lane >> 4;
  const int bid = blockIdx.x;

  if (bid < 2 || bid >= 6) {
    // ---------- rec0 (bid 0-1, chunk c) / rec1 (bid 6-7, chunk c-2) ----------
    const bool is0 = (bid < 2);
    if (is0) { if (c >= C_) return; }
    else     { if (c < 2) return; }
    const int ch = is0 ? c : (c - 2);
    const int grp = wv >> 2;            // 0/1: independent batch group
    const int qb = (wv & 3) * 4;        // 4 q-tiles (64 j-rows) per wave
    const int bbase = (is0 ? bid : bid - 6) * 32 + grp * 16;
    char* h0 = smem + grp * 16384;      // group's double-buffer
    char* h1 = h0 + 8192;

    uint4 wf[4][8];
    load_wfrag<4>(is0 ? Whh0 : Whh1, qb, bl, g, wf);
    u16* carry = (is0 ? carry0 : carry1) + (size_t)(bbase + bl) * H_;

    if (ch == 0) {  // zero first read-buffer (write-buffer is filled before read)
      uint4 z = make_uint4(0, 0, 0, 0);
      const int lt = (wv & 3) * 64 + lane;  // 0..255 within group
      ((uint4*)h0)[lt] = z;
      ((uint4*)h0)[lt + 256] = z;
    } else {
#pragma unroll
      for (int q = 0; q < 4; ++q) {
        const int j0 = (qb + q) * 16 + g * 4;
        uint2 hw = *(const uint2*)(carry + j0);
        *(uint2*)(h0 + SWZ(bl, j0 * 2)) = hw;
      }
    }

    float* prow = dout + (size_t)(bbase + bl) * T_ * H_ + (size_t)ch * S_ * H_;
    u16* rch = ring + ((size_t)(ch & 1) * S_) * (B_ * H_) + (size_t)(bbase + bl) * H_;
    float4 pr0[4], pr1[4];
#pragma unroll
    for (int q = 0; q < 4; ++q) {
      const int j0 = (qb + q) * 16 + g * 4;
      pr0[q] = *(const float4*)(prow + 0 * H_ + j0);
      pr1[q] = *(const float4*)(prow + 1 * H_ + j0);
    }
    __syncthreads();

    auto step = [&](int s, float4 (&pr)[4], char* rbuf, char* wbuf) {
      uint4 hf[8];
#pragma unroll
      for (int kc = 0; kc < 8; ++kc)
        hf[kc] = *(const uint4*)(rbuf + SWZ(bl, kc * 64 + g * 16));
      f32x4 accA[4], accB[4];
#pragma unroll
      for (int q = 0; q < 4; ++q) {
        accA[q] = (f32x4){0.f, 0.f, 0.f, 0.f};
        accB[q] = (f32x4){0.f, 0.f, 0.f, 0.f};
#pragma unroll
        for (int kc = 0; kc < 4; ++kc) {  // two 4-deep chains halve MFMA latency
          accA[q] = mfma4(wf[q][kc], hf[kc], accA[q]);
          accB[q] = mfma4(wf[q][kc + 4], hf[kc + 4], accB[q]);
        }
      }
#pragma unroll
      for (int q = 0; q < 4; ++q) {
        const int j0 = (qb + q) * 16 + g * 4;
        const float* pq = (const float*)&pr[q];
        float v0 = fast_tanh(accA[q][0] + accB[q][0] + pq[0]);
        float v1 = fast_tanh(accA[q][1] + accB[q][1] + pq[1]);
        float v2 = fast_tanh(accA[q][2] + accB[q][2] + pq[2]);
        float v3 = fast_tanh(accA[q][3] + accB[q][3] + pq[3]);
        uint2 hw; hw.x = cvtpk(v0, v1); hw.y = cvtpk(v2, v3);
        *(uint2*)(wbuf + SWZ(bl, j0 * 2)) = hw;                // h for s+1
        if (is0) {
          *(uint2*)(rch + (size_t)s * (B_ * H_) + j0) = hw;    // h0 -> ring
        } else {
          float4 o; o.x = v0; o.y = v1; o.z = v2; o.w = v3;
          *(float4*)(prow + (size_t)s * H_ + j0) = o;          // in-place h1 out
        }
        if (s + 2 < S_)
          pr[q] = *(const float4*)(prow + (size_t)(s + 2) * H_ + j0);
      }
      asm volatile("s_waitcnt lgkmcnt(0)" ::: "memory");
      __builtin_amdgcn_s_barrier();
      __builtin_amdgcn_sched_barrier(0);
    };
    for (int s = 0; s < S_; s += 2) {
      step(s, pr0, h0, h1);
      step(s + 1, pr1, h1, h0);
    }
    {  // carry out (final h in h0; S_ even; last barrier made it visible)
#pragma unroll
      for (int q = 0; q < 4; ++q) {
        const int j0 = (qb + q) * 16 + g * 4;
        uint2 hw = *(const uint2*)(h0 + SWZ(bl, j0 * 2));
        *(uint2*)(carry + j0) = hw;
      }
    }
  } else {
    // ---------- proj1: c1 = Wih1 . h0 + bias, chunk c-1 (throughput GEMM) ----------
    if (c < 1 || c > C_) return;
    const int pair = bid - 2;
    const int ch = c - 1;
    char* sb0 = smem;
    char* sb1 = smem + 8192;
    uint4 wf[2][8];
    load_wfrag<2>(Wih1, wv * 2, bl, g, wf);
    float4 cb[2];
#pragma unroll
    for (int q = 0; q < 2; ++q) {
      const int j0 = (wv * 2 + q) * 16 + g * 4;
      float4 a = *(const float4*)(bih1 + j0);
      float4 b = *(const float4*)(bhh1 + j0);
      cb[q].x = a.x + b.x; cb[q].y = a.y + b.y;
      cb[q].z = a.z + b.z; cb[q].w = a.w + b.w;
    }
    const u16* rbase2 = ring + ((size_t)(ch & 1) * S_) * (B_ * H_) + (size_t)pair * 16 * H_;
    const int sr = tid >> 5, scb = (tid & 31) * 16;  // stage: 16 rows x 512B
    uint4 v = *(const uint4*)(rbase2 + 0 * (B_ * H_) + (size_t)sr * H_ + (tid & 31) * 8);

    for (int s = 0; s < S_; ++s) {
      char* sb = (s & 1) ? sb1 : sb0;
      *(uint4*)(sb + SWZ(sr, scb)) = v;  // stage current (bf16 passthrough)
      __syncthreads();
      if (s + 1 < S_)
        v = *(const uint4*)(rbase2 + (size_t)(s + 1) * (B_ * H_) + (size_t)sr * H_ + (tid & 31) * 8);
      uint4 hf[8];
#pragma unroll
      for (int kc = 0; kc < 8; ++kc)
        hf[kc] = *(const uint4*)(sb + SWZ(bl, kc * 64 + g * 16));
      f32x4 acc[2];
#pragma unroll
      for (int q = 0; q < 2; ++q) {
        acc[q] = (f32x4){0.f, 0.f, 0.f, 0.f};
#pragma unroll
        for (int kc = 0; kc < 8; ++kc)
          acc[q] = mfma4(wf[q][kc], hf[kc], acc[q]);
      }
      float* od = dout + (size_t)(pair * 16 + bl) * T_ * H_ + (size_t)(ch * S_ + s) * H_;
#pragma unroll
      for (int q = 0; q < 2; ++q) {
        const int j0 = (wv * 2 + q) * 16 + g * 4;
        float4 o;
        o.x = acc[q][0] + cb[q].x; o.y = acc[q][1] + cb[q].y;
        o.z = acc[q][2] + cb[q].z; o.w = acc[q][3] + cb[q].w;
        *(float4*)(od + j0) = o;
      }
      __syncthreads();  // all reads done before s+2 overwrites this buffer
    }
  }
}

extern "C" void kernel_launch(void* const* d_in, const int* in_sizes, int n_in,
                              void* d_out, int out_size, void* d_ws, size_t ws_size,
                              hipStream_t stream) {
  (void)in_sizes; (void)n_in; (void)out_size;
  const float* x    = (const float*)d_in[0];
  const float* Wih0 = (const float*)d_in[1];
  const float* Whh0 = (const float*)d_in[2];
  const float* bih0 = (const float*)d_in[3];
  const float* bhh0 = (const float*)d_in[4];
  const float* Wih1 = (const float*)d_in[5];
  const float* Whh1 = (const float*)d_in[6];
  const float* bih1 = (const float*)d_in[7];
  const float* bhh1 = (const float*)d_in[8];
  float* out = (float*)d_out;

  const int TPW = 8;
  const int NWG = (B_ * T_) / (TPW * 16);  // 1024
  const size_t ring_elems = (size_t)2 * S_ * B_ * H_;     // 2 slots, bf16
  const size_t carry_elems = (size_t)B_ * H_;             // per layer
  const size_t need = (ring_elems + 2 * carry_elems) * sizeof(u16);  // ~4.26 MB

  pre_mfma<<<dim3(NWG), dim3(256), 0, stream>>>(x, Wih0, bih0, bhh0, out, TPW);
  if (ws_size >= need) {
    u16* ring = (u16*)d_ws;
    u16* carry0 = ring + ring_elems;
    u16* carry1 = carry0 + carry_elems;
    for (int c = 0; c <= C_ + 1; ++c)
      chunk3_k<<<dim3(8), dim3(512), 0, stream>>>(
          out, Whh0, Wih1, Whh1, bih1, bhh1, ring, carry0, carry1, c);
  } else {  // fallback: verified round-6 sequence
    rec_mfma<<<dim3(B_ / 16), dim3(512), 0, stream>>>(out, Whh0, out);
    pre_mfma<<<dim3(NWG), dim3(256), 0, stream>>>(out, Wih1, bih1, bhh1, out, TPW);
    rec_mfma<<<dim3(B_ / 16), dim3(512), 0, stream>>>(out, Whh1, out);
  }
}

// Round 11
// 2430.594 us; speedup vs baseline: 2.2814x; 2.2814x over previous
//
#include <hip/hip_runtime.h>
#include <stdint.h>

#define B_ 64
#define T_ 2048
#define H_ 256
#define S_ 64              // chunk length (timesteps)
#define C_ (T_ / S_)       // 32 chunks

typedef unsigned int u32;
typedef unsigned short u16;
typedef __attribute__((ext_vector_type(8))) short short8;
typedef __attribute__((ext_vector_type(4))) float f32x4;

// bf16 tile swizzle (verified rounds 4-9): conflict-free ds_read_b128 at
// (row=lane&15, slice=(lane>>4)*8); same formula on write and read.
#define SWZ(row, byte) (((row) * 512) + ((byte) ^ (((row) & 7) << 4)))

static __device__ __forceinline__ u32 cvtpk(float a, float b) {
  u32 d;
  asm("v_cvt_pk_bf16_f32 %0, %1, %2" : "=v"(d) : "v"(a), "v"(b));
  return d;
}
static __device__ __forceinline__ uint4 pack8(float4 a, float4 b) {
  uint4 r;
  r.x = cvtpk(a.x, a.y); r.y = cvtpk(a.z, a.w);
  r.z = cvtpk(b.x, b.y); r.w = cvtpk(b.z, b.w);
  return r;
}
static __device__ __forceinline__ short8 as8(uint4 v) {
  return __builtin_bit_cast(short8, v);
}
static __device__ __forceinline__ f32x4 mfma4(uint4 a, uint4 b, f32x4 c) {
  return __builtin_amdgcn_mfma_f32_16x16x32_bf16(as8(a), as8(b), c, 0, 0, 0);
}
// 1 - 2*rcp(e^{2x}+1); ~1ulp f32 << bf16 rounding; saturates correctly.
static __device__ __forceinline__ float fast_tanh(float x) {
  float e = __expf(2.0f * x);
  float r = __builtin_amdgcn_rcpf(e + 1.0f);
  return fmaf(-2.0f, r, 1.0f);
}

// Verified A/B fragment loader for mfma_f32_16x16x32_bf16 [m89/m91].
template <int NQ>
static __device__ __forceinline__ void load_wfrag(const float* W, int qbase, int bl,
                                                  int g, uint4 wf[NQ][8]) {
#pragma unroll
  for (int q = 0; q < NQ; ++q) {
    const float* wr = W + (size_t)((qbase + q) * 16 + bl) * H_ + g * 8;
#pragma unroll
    for (int kc = 0; kc < 8; ++kc) {
      float4 a = *(const float4*)(wr + kc * 32);
      float4 b = *(const float4*)(wr + kc * 32 + 4);
      wf[q][kc] = pack8(a, b);
    }
  }
}

// ---------------- proj0: pre0 = X . Wih0^T + b for ONE chunk slice ----------------
// 512 threads / 8 waves; 32-block slice: block bid2 handles batches
// {2*bid2, 2*bid2+1} x 4 tiles of 16 timesteps. Same staging + MFMA shape as
// the verified pre_mfma. Writes f32 pre0 into dout[chunk ch].
static __device__ void proj0_body(char* smem, const float* X, const float* Wih0,
                                  const float* bih0, const float* bhh0,
                                  float* dout, int ch, int bid2) {
  const int tid = threadIdx.x;
  const int lane = tid & 63, wv = tid >> 6;
  const int bl = lane & 15, g = lane >> 4;
  char* sb0 = smem;
  char* sb1 = smem + 8192;

  uint4 wf[2][8];
  load_wfrag<2>(Wih0, wv * 2, bl, g, wf);
  float4 cb[2];
#pragma unroll
  for (int q = 0; q < 2; ++q) {
    const int j0 = (wv * 2 + q) * 16 + g * 4;
    float4 a = *(const float4*)(bih0 + j0);
    float4 b = *(const float4*)(bhh0 + j0);
    cb[q].x = a.x + b.x; cb[q].y = a.y + b.y;
    cb[q].z = a.z + b.z; cb[q].w = a.w + b.w;
  }

  const int sr = tid >> 5, sc8 = (tid & 31) * 8;  // stage: 16 rows x 32 lanes x 8 f32
  auto rowbase = [&](int it) -> size_t {
    const int b = bid2 * 2 + (it >> 2), i = it & 3;
    return (size_t)(b * T_ + ch * S_ + i * 16);
  };
  float4 s0, s1;
  {
    const float4* xs = (const float4*)(X + (rowbase(0) + sr) * H_ + sc8);
    s0 = xs[0]; s1 = xs[1];
  }

  for (int it = 0; it < 8; ++it) {
    char* sb = (it & 1) ? sb1 : sb0;
    *(uint4*)(sb + SWZ(sr, sc8 * 2)) = pack8(s0, s1);
    __syncthreads();
    if (it + 1 < 8) {
      const float4* xn = (const float4*)(X + (rowbase(it + 1) + sr) * H_ + sc8);
      s0 = xn[0]; s1 = xn[1];
    }
    uint4 hf[8];
#pragma unroll
    for (int kc = 0; kc < 8; ++kc)
      hf[kc] = *(const uint4*)(sb + SWZ(bl, kc * 64 + g * 16));
    f32x4 acc[2];
#pragma unroll
    for (int q = 0; q < 2; ++q) {
      acc[q] = (f32x4){0.f, 0.f, 0.f, 0.f};
#pragma unroll
      for (int kc = 0; kc < 8; ++kc)
        acc[q] = mfma4(wf[q][kc], hf[kc], acc[q]);
    }
    float* od = dout + (rowbase(it) + bl) * H_;
#pragma unroll
    for (int q = 0; q < 2; ++q) {
      const int j0 = (wv * 2 + q) * 16 + g * 4;
      float4 o;
      o.x = acc[q][0] + cb[q].x; o.y = acc[q][1] + cb[q].y;
      o.z = acc[q][2] + cb[q].z; o.w = acc[q][3] + cb[q].w;
      *(float4*)(od + j0) = o;
    }
    __syncthreads();
  }
}

__global__ __launch_bounds__(512, 1) void pre_chunk0(const float* X, const float* Wih0,
                                                     const float* bih0, const float* bhh0,
                                                     float* dout) {
  __shared__ __align__(16) char smem[2 * 8192];
  proj0_body(smem, X, Wih0, bih0, bhh0, dout, 0, blockIdx.x);
}

// ---------------- layer-0 pre-projection over full T (fallback only) ----------------
__global__ __launch_bounds__(256, 2) void pre_mfma(const float* X, const float* W,
                                                   const float* bi, const float* bh,
                                                   float* P, int tpw) {
  __shared__ char sb_[2][8192];
  const int tid = threadIdx.x;
  const int lane = tid & 63, wv = tid >> 6;
  const int bl = lane & 15, g = lane >> 4;

  uint4 wf[4][8];
  load_wfrag<4>(W, wv * 4, bl, g, wf);
  float4 bias[4];
#pragma unroll
  for (int q = 0; q < 4; ++q) {
    const int j0 = (wv * 4 + q) * 16 + g * 4;
    float4 a = *(const float4*)(bi + j0);
    float4 c = *(const float4*)(bh + j0);
    bias[q].x = a.x + c.x; bias[q].y = a.y + c.y;
    bias[q].z = a.z + c.z; bias[q].w = a.w + c.w;
  }

  const size_t row0 = (size_t)blockIdx.x * tpw * 16;
  const int sr = tid >> 4, sc = (tid & 15) * 16;
  float4 s0, s1, s2, s3;
  {
    const float4* xs = (const float4*)(X + (row0 + sr) * H_ + sc);
    s0 = xs[0]; s1 = xs[1]; s2 = xs[2]; s3 = xs[3];
  }

  for (int i = 0; i < tpw; ++i) {
    char* sb = sb_[i & 1];
    *(uint4*)(sb + SWZ(sr, sc * 2)) = pack8(s0, s1);
    *(uint4*)(sb + SWZ(sr, sc * 2 + 16)) = pack8(s2, s3);
    __syncthreads();
    if (i + 1 < tpw) {
      const float4* xn = (const float4*)(X + (row0 + (i + 1) * 16 + sr) * H_ + sc);
      s0 = xn[0]; s1 = xn[1]; s2 = xn[2]; s3 = xn[3];
    }
    uint4 hf[8];
#pragma unroll
    for (int kc = 0; kc < 8; ++kc)
      hf[kc] = *(const uint4*)(sb + SWZ(bl, kc * 64 + g * 16));
    f32x4 acc[4];
#pragma unroll
    for (int q = 0; q < 4; ++q) {
      acc[q] = (f32x4){0.f, 0.f, 0.f, 0.f};
#pragma unroll
      for (int kc = 0; kc < 8; ++kc)
        acc[q] = mfma4(wf[q][kc], hf[kc], acc[q]);
    }
#pragma unroll
    for (int q = 0; q < 4; ++q) {
      const int j0 = (wv * 4 + q) * 16 + g * 4;
      float4 o;
      o.x = acc[q][0] + bias[q].x; o.y = acc[q][1] + bias[q].y;
      o.z = acc[q][2] + bias[q].z; o.w = acc[q][3] + bias[q].w;
      *(float4*)(P + (row0 + i * 16 + bl) * H_ + j0) = o;
    }
    __syncthreads();
  }
}

// ---------------- fallback standalone recurrence (round-6, verified) ----------------
__global__ __launch_bounds__(512, 1) void rec_mfma(const float* pre, const float* W,
                                                   float* out) {
  __shared__ char hb_[2][8192];
  const int tid = threadIdx.x;
  const int lane = tid & 63, wv = tid >> 6;
  const int bl = lane & 15, g = lane >> 4;
  const int b0 = blockIdx.x * 16;

  uint4 wf[2][8];
  load_wfrag<2>(W, wv * 2, bl, g, wf);
  {
    uint4 z = make_uint4(0, 0, 0, 0);
    ((uint4*)hb_[0])[tid] = z;
    ((uint4*)hb_[1])[tid] = z;
  }
  const float* prow = pre + (size_t)(b0 + bl) * T_ * H_;
  float* orow = out + (size_t)(b0 + bl) * T_ * H_;
  float4 pr0[2], pr1[2];
#pragma unroll
  for (int q = 0; q < 2; ++q) {
    const int j0 = (wv * 2 + q) * 16 + g * 4;
    pr0[q] = *(const float4*)(prow + 0 * H_ + j0);
    pr1[q] = *(const float4*)(prow + 1 * H_ + j0);
  }
  __syncthreads();

  auto step = [&](int t, float4 (&pr)[2], char* rbuf, char* wbuf) {
    uint4 hf[8];
#pragma unroll
    for (int kc = 0; kc < 8; ++kc)
      hf[kc] = *(const uint4*)(rbuf + SWZ(bl, kc * 64 + g * 16));
    f32x4 accA[2], accB[2];
#pragma unroll
    for (int q = 0; q < 2; ++q) {
      accA[q] = (f32x4){0.f, 0.f, 0.f, 0.f};
      accB[q] = (f32x4){0.f, 0.f, 0.f, 0.f};
#pragma unroll
      for (int kc = 0; kc < 4; ++kc) {
        accA[q] = mfma4(wf[q][kc], hf[kc], accA[q]);
        accB[q] = mfma4(wf[q][kc + 4], hf[kc + 4], accB[q]);
      }
    }
#pragma unroll
    for (int q = 0; q < 2; ++q) {
      const int j0 = (wv * 2 + q) * 16 + g * 4;
      const float* pq = (const float*)&pr[q];
      float v0 = fast_tanh(accA[q][0] + accB[q][0] + pq[0]);
      float v1 = fast_tanh(accA[q][1] + accB[q][1] + pq[1]);
      float v2 = fast_tanh(accA[q][2] + accB[q][2] + pq[2]);
      float v3 = fast_tanh(accA[q][3] + accB[q][3] + pq[3]);
      uint2 hw; hw.x = cvtpk(v0, v1); hw.y = cvtpk(v2, v3);
      *(uint2*)(wbuf + SWZ(bl, j0 * 2)) = hw;
      float4 o; o.x = v0; o.y = v1; o.z = v2; o.w = v3;
      *(float4*)(orow + (size_t)t * H_ + j0) = o;
      if (t + 2 < T_)
        pr[q] = *(const float4*)(prow + (size_t)(t + 2) * H_ + j0);
    }
    asm volatile("s_waitcnt lgkmcnt(0)" ::: "memory");
    __builtin_amdgcn_s_barrier();
    __builtin_amdgcn_sched_barrier(0);
  };

  for (int t = 0; t < T_; t += 2) {
    step(t, pr0, hb_[0], hb_[1]);
    step(t + 1, pr1, hb_[1], hb_[0]);
  }
}

// ---------------- 4-stage chunk pipeline kernel ----------------
// Kernel c: blocks 0-3 rec0(chunk c) -> h0 bf16 ring; blocks 4-7 proj1
// (chunk c-1): c1 = Wih1*h0 + b -> f32 into d_out[chunk c-1]; blocks 8-11
// rec1(chunk c-2): round-6 in-place recurrence on d_out; blocks 12-43
// proj0(chunk c+1): pre0 = X*Wih0^T + b -> f32 into d_out[chunk c+1].
// Each d_out region: pre0 (kernel ch-1) -> read by rec0 (ch) -> c1 (ch+1)
// -> h1 (ch+2). All cross-stage data crosses a kernel boundary (G16);
// deterministic & graph-replay safe.
__global__ __launch_bounds__(512, 1) void chunk4_k(
    const float* X, float* dout, const float* Wih0, const float* bih0,
    const float* bhh0, const float* Whh0, const float* Wih1, const float* Whh1,
    const float* bih1, const float* bhh1,
    u16* ring, u16* carry0, u16* carry1, int c) {
  __shared__ __align__(16) char smem[2 * 8192];
  const int tid = threadIdx.x;
  const int lane = tid & 63, wv = tid >> 6;
  const int bl = lane & 15, g = lane >> 4;
  const int bid = blockIdx.x;
  char* sb0 = smem;
  char* sb1 = smem + 8192;

  if (bid < 4) {
    // ---------- rec0: layer-0 recurrence, chunk c ----------
    if (c >= C_) return;
    const int pair = bid;
    uint4 wf[2][8];
    load_wfrag<2>(Whh0, wv * 2, bl, g, wf);
    if (c == 0) {
      uint4 z = make_uint4(0, 0, 0, 0);
      ((uint4*)sb0)[tid] = z;  // 512 x 16B = full 8KB
    } else {
      const u16* cr = carry0 + pair * 16 * H_ + bl * H_;
#pragma unroll
      for (int q = 0; q < 2; ++q) {
        const int j0 = (wv * 2 + q) * 16 + g * 4;
        uint2 hw = *(const uint2*)(cr + j0);
        *(uint2*)(sb0 + SWZ(bl, j0 * 2)) = hw;
      }
    }
    const float* prow = dout + (size_t)(pair * 16 + bl) * T_ * H_ + (size_t)c * S_ * H_;
    u16* rch = ring + ((size_t)(c & 1) * S_) * (B_ * H_) + (size_t)(pair * 16 + bl) * H_;
    float4 pr0[2], pr1[2];
#pragma unroll
    for (int q = 0; q < 2; ++q) {
      const int j0 = (wv * 2 + q) * 16 + g * 4;
      pr0[q] = *(const float4*)(prow + 0 * H_ + j0);
      pr1[q] = *(const float4*)(prow + 1 * H_ + j0);
    }
    __syncthreads();

    auto step = [&](int s, float4 (&pr)[2], char* rbuf, char* wbuf) {
      uint4 hf[8];
#pragma unroll
      for (int kc = 0; kc < 8; ++kc)
        hf[kc] = *(const uint4*)(rbuf + SWZ(bl, kc * 64 + g * 16));
      f32x4 accA[2], accB[2];
#pragma unroll
      for (int q = 0; q < 2; ++q) {
        accA[q] = (f32x4){0.f, 0.f, 0.f, 0.f};
        accB[q] = (f32x4){0.f, 0.f, 0.f, 0.f};
#pragma unroll
        for (int kc = 0; kc < 4; ++kc) {
          accA[q] = mfma4(wf[q][kc], hf[kc], accA[q]);
          accB[q] = mfma4(wf[q][kc + 4], hf[kc + 4], accB[q]);
        }
      }
#pragma unroll
      for (int q = 0; q < 2; ++q) {
        const int j0 = (wv * 2 + q) * 16 + g * 4;
        const float* pq = (const float*)&pr[q];
        float v0 = fast_tanh(accA[q][0] + accB[q][0] + pq[0]);
        float v1 = fast_tanh(accA[q][1] + accB[q][1] + pq[1]);
        float v2 = fast_tanh(accA[q][2] + accB[q][2] + pq[2]);
        float v3 = fast_tanh(accA[q][3] + accB[q][3] + pq[3]);
        uint2 hw; hw.x = cvtpk(v0, v1); hw.y = cvtpk(v2, v3);
        *(uint2*)(wbuf + SWZ(bl, j0 * 2)) = hw;             // h0 for s+1
        *(uint2*)(rch + (size_t)s * (B_ * H_) + j0) = hw;   // h0 -> ring
        if (s + 2 < S_)
          pr[q] = *(const float4*)(prow + (size_t)(s + 2) * H_ + j0);
      }
      asm volatile("s_waitcnt lgkmcnt(0)" ::: "memory");
      __builtin_amdgcn_s_barrier();
      __builtin_amdgcn_sched_barrier(0);
    };
    for (int s = 0; s < S_; s += 2) {
      step(s, pr0, sb0, sb1);
      step(s + 1, pr1, sb1, sb0);
    }
    {  // carry out (final h in sb0; S_ even; last barrier made it visible)
      u16* cw = carry0 + pair * 16 * H_ + bl * H_;
#pragma unroll
      for (int q = 0; q < 2; ++q) {
        const int j0 = (wv * 2 + q) * 16 + g * 4;
        uint2 hw = *(const uint2*)(sb0 + SWZ(bl, j0 * 2));
        *(uint2*)(cw + j0) = hw;
      }
    }
  } else if (bid < 8) {
    // ---------- proj1: c1 = Wih1 . h0 + bias, chunk c-1 (throughput GEMM) ----------
    if (c < 1 || c > C_) return;
    const int pair = bid - 4;
    const int ch = c - 1;
    uint4 wf[2][8];
    load_wfrag<2>(Wih1, wv * 2, bl, g, wf);
    float4 cb[2];
#pragma unroll
    for (int q = 0; q < 2; ++q) {
      const int j0 = (wv * 2 + q) * 16 + g * 4;
      float4 a = *(const float4*)(bih1 + j0);
      float4 b = *(const float4*)(bhh1 + j0);
      cb[q].x = a.x + b.x; cb[q].y = a.y + b.y;
      cb[q].z = a.z + b.z; cb[q].w = a.w + b.w;
    }
    const u16* rbase2 = ring + ((size_t)(ch & 1) * S_) * (B_ * H_) + (size_t)pair * 16 * H_;
    const int sr = tid >> 5, scb = (tid & 31) * 16;  // stage: 16 rows x 512B
    uint4 v = *(const uint4*)(rbase2 + 0 * (B_ * H_) + (size_t)sr * H_ + (tid & 31) * 8);

    for (int s = 0; s < S_; ++s) {
      char* sb = (s & 1) ? sb1 : sb0;
      *(uint4*)(sb + SWZ(sr, scb)) = v;  // stage current (bf16 passthrough)
      __syncthreads();
      if (s + 1 < S_)
        v = *(const uint4*)(rbase2 + (size_t)(s + 1) * (B_ * H_) + (size_t)sr * H_ + (tid & 31) * 8);
      uint4 hf[8];
#pragma unroll
      for (int kc = 0; kc < 8; ++kc)
        hf[kc] = *(const uint4*)(sb + SWZ(bl, kc * 64 + g * 16));
      f32x4 acc[2];
#pragma unroll
      for (int q = 0; q < 2; ++q) {
        acc[q] = (f32x4){0.f, 0.f, 0.f, 0.f};
#pragma unroll
        for (int kc = 0; kc < 8; ++kc)
          acc[q] = mfma4(wf[q][kc], hf[kc], acc[q]);
      }
      float* od = dout + (size_t)(pair * 16 + bl) * T_ * H_ + (size_t)(ch * S_ + s) * H_;
#pragma unroll
      for (int q = 0; q < 2; ++q) {
        const int j0 = (wv * 2 + q) * 16 + g * 4;
        float4 o;
        o.x = acc[q][0] + cb[q].x; o.y = acc[q][1] + cb[q].y;
        o.z = acc[q][2] + cb[q].z; o.w = acc[q][3] + cb[q].w;
        *(float4*)(od + j0) = o;
      }
      __syncthreads();  // all reads done before s+2 overwrites this buffer
    }
  } else if (bid < 12) {
    // ---------- rec1: layer-1 recurrence, chunk c-2, in-place on d_out ----------
    if (c < 2) return;
    const int pair = bid - 8;
    const int ch = c - 2;
    uint4 wf[2][8];
    load_wfrag<2>(Whh1, wv * 2, bl, g, wf);
    if (ch == 0) {
      uint4 z = make_uint4(0, 0, 0, 0);
      ((uint4*)sb0)[tid] = z;
    } else {
      const u16* cr = carry1 + pair * 16 * H_ + bl * H_;
#pragma unroll
      for (int q = 0; q < 2; ++q) {
        const int j0 = (wv * 2 + q) * 16 + g * 4;
        uint2 hw = *(const uint2*)(cr + j0);
        *(uint2*)(sb0 + SWZ(bl, j0 * 2)) = hw;
      }
    }
    float* prow = dout + (size_t)(pair * 16 + bl) * T_ * H_ + (size_t)ch * S_ * H_;
    float4 pr0[2], pr1[2];
#pragma unroll
    for (int q = 0; q < 2; ++q) {
      const int j0 = (wv * 2 + q) * 16 + g * 4;
      pr0[q] = *(const float4*)(prow + 0 * H_ + j0);
      pr1[q] = *(const float4*)(prow + 1 * H_ + j0);
    }
    __syncthreads();

    auto step = [&](int s, float4 (&pr)[2], char* rbuf, char* wbuf) {
      uint4 hf[8];
#pragma unroll
      for (int kc = 0; kc < 8; ++kc)
        hf[kc] = *(const uint4*)(rbuf + SWZ(bl, kc * 64 + g * 16));
      f32x4 accA[2], accB[2];
#pragma unroll
      for (int q = 0; q < 2; ++q) {
        accA[q] = (f32x4){0.f, 0.f, 0.f, 0.f};
        accB[q] = (f32x4){0.f, 0.f, 0.f, 0.f};
#pragma unroll
        for (int kc = 0; kc < 4; ++kc) {
          accA[q] = mfma4(wf[q][kc], hf[kc], accA[q]);
          accB[q] = mfma4(wf[q][kc + 4], hf[kc + 4], accB[q]);
        }
      }
#pragma unroll
      for (int q = 0; q < 2; ++q) {
        const int j0 = (wv * 2 + q) * 16 + g * 4;
        const float* pq = (const float*)&pr[q];
        float v0 = fast_tanh(accA[q][0] + accB[q][0] + pq[0]);
        float v1 = fast_tanh(accA[q][1] + accB[q][1] + pq[1]);
        float v2 = fast_tanh(accA[q][2] + accB[q][2] + pq[2]);
        float v3 = fast_tanh(accA[q][3] + accB[q][3] + pq[3]);
        uint2 hw; hw.x = cvtpk(v0, v1); hw.y = cvtpk(v2, v3);
        *(uint2*)(wbuf + SWZ(bl, j0 * 2)) = hw;         // h1 for s+1
        float4 o; o.x = v0; o.y = v1; o.z = v2; o.w = v3;
        *(float4*)(prow + (size_t)s * H_ + j0) = o;     // in-place h1 out
        if (s + 2 < S_)
          pr[q] = *(const float4*)(prow + (size_t)(s + 2) * H_ + j0);  // c1 lead-2
      }
      asm volatile("s_waitcnt lgkmcnt(0)" ::: "memory");
      __builtin_amdgcn_s_barrier();
      __builtin_amdgcn_sched_barrier(0);
    };
    for (int s = 0; s < S_; s += 2) {
      step(s, pr0, sb0, sb1);
      step(s + 1, pr1, sb1, sb0);
    }
    {  // carry out final h1
      u16* cw = carry1 + pair * 16 * H_ + bl * H_;
#pragma unroll
      for (int q = 0; q < 2; ++q) {
        const int j0 = (wv * 2 + q) * 16 + g * 4;
        uint2 hw = *(const uint2*)(sb0 + SWZ(bl, j0 * 2));
        *(uint2*)(cw + j0) = hw;
      }
    }
  } else {
    // ---------- proj0: pre0 for chunk c+1 (throughput GEMM on idle CUs) ----------
    if (c + 1 > C_ - 1) return;
    proj0_body(smem, X, Wih0, bih0, bhh0, dout, c + 1, bid - 12);
  }
}

extern "C" void kernel_launch(void* const* d_in, const int* in_sizes, int n_in,
                              void* d_out, int out_size, void* d_ws, size_t ws_size,
                              hipStream_t stream) {
  (void)in_sizes; (void)n_in; (void)out_size;
  const float* x    = (const float*)d_in[0];
  const float* Wih0 = (const float*)d_in[1];
  const float* Whh0 = (const float*)d_in[2];
  const float* bih0 = (const float*)d_in[3];
  const float* bhh0 = (const float*)d_in[4];
  const float* Wih1 = (const float*)d_in[5];
  const float* Whh1 = (const float*)d_in[6];
  const float* bih1 = (const float*)d_in[7];
  const float* bhh1 = (const float*)d_in[8];
  float* out = (float*)d_out;

  const size_t ring_elems = (size_t)2 * S_ * B_ * H_;     // 2 slots, bf16
  const size_t carry_elems = (size_t)B_ * H_;             // per layer
  const size_t need = (ring_elems + 2 * carry_elems) * sizeof(u16);  // ~4.26 MB

  if (ws_size >= need) {
    u16* ring = (u16*)d_ws;
    u16* carry0 = ring + ring_elems;
    u16* carry1 = carry0 + carry_elems;
    pre_chunk0<<<dim3(32), dim3(512), 0, stream>>>(x, Wih0, bih0, bhh0, out);
    for (int c = 0; c <= C_ + 1; ++c)
      chunk4_k<<<dim3(44), dim3(512), 0, stream>>>(
          x, out, Wih0, bih0, bhh0, Whh0, Wih1, Whh1, bih1, bhh1,
          ring, carry0, carry1, c);
  } else {  // fallback: verified round-6 sequence
    const int TPW = 8;
    const int NWG = (B_ * T_) / (TPW * 16);  // 1024
    pre_mfma<<<dim3(NWG), dim3(256), 0, stream>>>(x, Wih0, bih0, bhh0, out, TPW);
    rec_mfma<<<dim3(B_ / 16), dim3(512), 0, stream>>>(out, Whh0, out);
    pre_mfma<<<dim3(NWG), dim3(256), 0, stream>>>(out, Wih1, bih1, bhh1, out, TPW);
    rec_mfma<<<dim3(B_ / 16), dim3(512), 0, stream>>>(out, Whh1, out);
  }
}

// Round 12
// 2153.591 us; speedup vs baseline: 2.5748x; 1.1286x over previous
//
#include <hip/hip_runtime.h>
#include <stdint.h>

#define B_ 64
#define T_ 2048
#define H_ 256
#define S_ 64              // chunk length (timesteps)
#define C_ (T_ / S_)       // 32 chunks

typedef unsigned int u32;
typedef unsigned short u16;
typedef __attribute__((ext_vector_type(8))) short short8;
typedef __attribute__((ext_vector_type(4))) float f32x4;

// bf16 tile swizzle (verified rounds 4-11): conflict-free ds_read_b128 at
// (row=lane&15, slice=(lane>>4)*8); same formula on write and read.
#define SWZ(row, byte) (((row) * 512) + ((byte) ^ (((row) & 7) << 4)))

static __device__ __forceinline__ u32 cvtpk(float a, float b) {
  u32 d;
  asm("v_cvt_pk_bf16_f32 %0, %1, %2" : "=v"(d) : "v"(a), "v"(b));
  return d;
}
static __device__ __forceinline__ uint4 pack8(float4 a, float4 b) {
  uint4 r;
  r.x = cvtpk(a.x, a.y); r.y = cvtpk(a.z, a.w);
  r.z = cvtpk(b.x, b.y); r.w = cvtpk(b.z, b.w);
  return r;
}
static __device__ __forceinline__ short8 as8(uint4 v) {
  return __builtin_bit_cast(short8, v);
}
static __device__ __forceinline__ f32x4 mfma4(uint4 a, uint4 b, f32x4 c) {
  return __builtin_amdgcn_mfma_f32_16x16x32_bf16(as8(a), as8(b), c, 0, 0, 0);
}
// 1 - 2*rcp(e^{2x}+1); ~1ulp f32 << bf16 rounding; saturates correctly.
static __device__ __forceinline__ float fast_tanh(float x) {
  float e = __expf(2.0f * x);
  float r = __builtin_amdgcn_rcpf(e + 1.0f);
  return fmaf(-2.0f, r, 1.0f);
}

// Verified A/B fragment loader for mfma_f32_16x16x32_bf16 [m89/m91].
template <int NQ>
static __device__ __forceinline__ void load_wfrag(const float* W, int qbase, int bl,
                                                  int g, uint4 wf[NQ][8]) {
#pragma unroll
  for (int q = 0; q < NQ; ++q) {
    const float* wr = W + (size_t)((qbase + q) * 16 + bl) * H_ + g * 8;
#pragma unroll
    for (int kc = 0; kc < 8; ++kc) {
      float4 a = *(const float4*)(wr + kc * 32);
      float4 b = *(const float4*)(wr + kc * 32 + 4);
      wf[q][kc] = pack8(a, b);
    }
  }
}

// ---- chunk-granularity cross-WG handshake (round-7/8-validated pattern) ----
static __device__ __forceinline__ void wait_ge(u32* f, u32 tgt) {
  if (__hip_atomic_load(f, __ATOMIC_ACQUIRE, __HIP_MEMORY_SCOPE_AGENT) >= tgt) return;
  while (__hip_atomic_load(f, __ATOMIC_ACQUIRE, __HIP_MEMORY_SCOPE_AGENT) < tgt)
    __builtin_amdgcn_s_sleep(8);
}
static __device__ __forceinline__ void drain_all() {
  asm volatile("s_waitcnt vmcnt(0) lgkmcnt(0)" ::: "memory");
  __builtin_amdgcn_s_barrier();  // every wave's stores complete before flag
}
static __device__ __forceinline__ void publish_val(u32* f, u32 v) {
  drain_all();
  if (threadIdx.x == 0)
    __hip_atomic_store(f, v, __ATOMIC_RELEASE, __HIP_MEMORY_SCOPE_AGENT);
}
static __device__ __forceinline__ void publish_add(u32* f) {
  drain_all();
  if (threadIdx.x == 0)
    (void)__hip_atomic_fetch_add(f, 1u, __ATOMIC_RELEASE, __HIP_MEMORY_SCOPE_AGENT);
}

__global__ void init_flags(u32* f) { f[threadIdx.x] = 0; }  // 1024 threads = 4KB

// ---------------- proj0 body: pre0 = X.Wih0^T + b for one chunk slice ----------------
static __device__ void proj0_body(char* smem, const float* X, const float* Wih0,
                                  const float* bih0, const float* bhh0,
                                  float* dout, int ch, int bid2,
                                  const uint4 wf[2][8], const float4 cb[2]) {
  const int tid = threadIdx.x;
  const int lane = tid & 63, wv = tid >> 6;
  const int bl = lane & 15, g = lane >> 4;
  char* sb0 = smem;
  char* sb1 = smem + 8192;

  const int sr = tid >> 5, sc8 = (tid & 31) * 8;
  auto rowbase = [&](int it) -> size_t {
    const int b = bid2 * 2 + (it >> 2), i = it & 3;
    return (size_t)(b * T_ + ch * S_ + i * 16);
  };
  float4 s0, s1;
  {
    const float4* xs = (const float4*)(X + (rowbase(0) + sr) * H_ + sc8);
    s0 = xs[0]; s1 = xs[1];
  }
  for (int it = 0; it < 8; ++it) {
    char* sb = (it & 1) ? sb1 : sb0;
    *(uint4*)(sb + SWZ(sr, sc8 * 2)) = pack8(s0, s1);
    __syncthreads();
    if (it + 1 < 8) {
      const float4* xn = (const float4*)(X + (rowbase(it + 1) + sr) * H_ + sc8);
      s0 = xn[0]; s1 = xn[1];
    }
    uint4 hf[8];
#pragma unroll
    for (int kc = 0; kc < 8; ++kc)
      hf[kc] = *(const uint4*)(sb + SWZ(bl, kc * 64 + g * 16));
    f32x4 acc[2];
#pragma unroll
    for (int q = 0; q < 2; ++q) {
      acc[q] = (f32x4){0.f, 0.f, 0.f, 0.f};
#pragma unroll
      for (int kc = 0; kc < 8; ++kc)
        acc[q] = mfma4(wf[q][kc], hf[kc], acc[q]);
    }
    float* od = dout + (rowbase(it) + bl) * H_;
#pragma unroll
    for (int q = 0; q < 2; ++q) {
      const int j0 = (wv * 2 + q) * 16 + g * 4;
      float4 o;
      o.x = acc[q][0] + cb[q].x; o.y = acc[q][1] + cb[q].y;
      o.z = acc[q][2] + cb[q].z; o.w = acc[q][3] + cb[q].w;
      *(float4*)(od + j0) = o;
    }
    __syncthreads();
  }
}

// ---------------- fallback: full-T projection + recurrence (round-6, verified) ----------------
__global__ __launch_bounds__(256, 2) void pre_mfma(const float* X, const float* W,
                                                   const float* bi, const float* bh,
                                                   float* P, int tpw) {
  __shared__ char sb_[2][8192];
  const int tid = threadIdx.x;
  const int lane = tid & 63, wv = tid >> 6;
  const int bl = lane & 15, g = lane >> 4;

  uint4 wf[4][8];
  load_wfrag<4>(W, wv * 4, bl, g, wf);
  float4 bias[4];
#pragma unroll
  for (int q = 0; q < 4; ++q) {
    const int j0 = (wv * 4 + q) * 16 + g * 4;
    float4 a = *(const float4*)(bi + j0);
    float4 c = *(const float4*)(bh + j0);
    bias[q].x = a.x + c.x; bias[q].y = a.y + c.y;
    bias[q].z = a.z + c.z; bias[q].w = a.w + c.w;
  }
  const size_t row0 = (size_t)blockIdx.x * tpw * 16;
  const int sr = tid >> 4, sc = (tid & 15) * 16;
  float4 s0, s1, s2, s3;
  {
    const float4* xs = (const float4*)(X + (row0 + sr) * H_ + sc);
    s0 = xs[0]; s1 = xs[1]; s2 = xs[2]; s3 = xs[3];
  }
  for (int i = 0; i < tpw; ++i) {
    char* sb = sb_[i & 1];
    *(uint4*)(sb + SWZ(sr, sc * 2)) = pack8(s0, s1);
    *(uint4*)(sb + SWZ(sr, sc * 2 + 16)) = pack8(s2, s3);
    __syncthreads();
    if (i + 1 < tpw) {
      const float4* xn = (const float4*)(X + (row0 + (i + 1) * 16 + sr) * H_ + sc);
      s0 = xn[0]; s1 = xn[1]; s2 = xn[2]; s3 = xn[3];
    }
    uint4 hf[8];
#pragma unroll
    for (int kc = 0; kc < 8; ++kc)
      hf[kc] = *(const uint4*)(sb + SWZ(bl, kc * 64 + g * 16));
    f32x4 acc[4];
#pragma unroll
    for (int q = 0; q < 4; ++q) {
      acc[q] = (f32x4){0.f, 0.f, 0.f, 0.f};
#pragma unroll
      for (int kc = 0; kc < 8; ++kc)
        acc[q] = mfma4(wf[q][kc], hf[kc], acc[q]);
    }
#pragma unroll
    for (int q = 0; q < 4; ++q) {
      const int j0 = (wv * 4 + q) * 16 + g * 4;
      float4 o;
      o.x = acc[q][0] + bias[q].x; o.y = acc[q][1] + bias[q].y;
      o.z = acc[q][2] + bias[q].z; o.w = acc[q][3] + bias[q].w;
      *(float4*)(P + (row0 + i * 16 + bl) * H_ + j0) = o;
    }
    __syncthreads();
  }
}

__global__ __launch_bounds__(512, 1) void rec_mfma(const float* pre, const float* W,
                                                   float* out) {
  __shared__ char hb_[2][8192];
  const int tid = threadIdx.x;
  const int lane = tid & 63, wv = tid >> 6;
  const int bl = lane & 15, g = lane >> 4;
  const int b0 = blockIdx.x * 16;

  uint4 wf[2][8];
  load_wfrag<2>(W, wv * 2, bl, g, wf);
  {
    uint4 z = make_uint4(0, 0, 0, 0);
    ((uint4*)hb_[0])[tid] = z;
    ((uint4*)hb_[1])[tid] = z;
  }
  const float* prow = pre + (size_t)(b0 + bl) * T_ * H_;
  float* orow = out + (size_t)(b0 + bl) * T_ * H_;
  float4 pr0[2], pr1[2];
#pragma unroll
  for (int q = 0; q < 2; ++q) {
    const int j0 = (wv * 2 + q) * 16 + g * 4;
    pr0[q] = *(const float4*)(prow + 0 * H_ + j0);
    pr1[q] = *(const float4*)(prow + 1 * H_ + j0);
  }
  __syncthreads();

  auto step = [&](int t, float4 (&pr)[2], char* rbuf, char* wbuf) {
    uint4 hf[8];
#pragma unroll
    for (int kc = 0; kc < 8; ++kc)
      hf[kc] = *(const uint4*)(rbuf + SWZ(bl, kc * 64 + g * 16));
    f32x4 accA[2], accB[2];
#pragma unroll
    for (int q = 0; q < 2; ++q) {
      accA[q] = (f32x4){0.f, 0.f, 0.f, 0.f};
      accB[q] = (f32x4){0.f, 0.f, 0.f, 0.f};
#pragma unroll
      for (int kc = 0; kc < 4; ++kc) {
        accA[q] = mfma4(wf[q][kc], hf[kc], accA[q]);
        accB[q] = mfma4(wf[q][kc + 4], hf[kc + 4], accB[q]);
      }
    }
#pragma unroll
    for (int q = 0; q < 2; ++q) {
      const int j0 = (wv * 2 + q) * 16 + g * 4;
      const float* pq = (const float*)&pr[q];
      float v0 = fast_tanh(accA[q][0] + accB[q][0] + pq[0]);
      float v1 = fast_tanh(accA[q][1] + accB[q][1] + pq[1]);
      float v2 = fast_tanh(accA[q][2] + accB[q][2] + pq[2]);
      float v3 = fast_tanh(accA[q][3] + accB[q][3] + pq[3]);
      uint2 hw; hw.x = cvtpk(v0, v1); hw.y = cvtpk(v2, v3);
      *(uint2*)(wbuf + SWZ(bl, j0 * 2)) = hw;
      float4 o; o.x = v0; o.y = v1; o.z = v2; o.w = v3;
      *(float4*)(orow + (size_t)t * H_ + j0) = o;
      if (t + 2 < T_)
        pr[q] = *(const float4*)(prow + (size_t)(t + 2) * H_ + j0);
    }
    asm volatile("s_waitcnt lgkmcnt(0)" ::: "memory");
    __builtin_amdgcn_s_barrier();
    __builtin_amdgcn_sched_barrier(0);
  };
  for (int t = 0; t < T_; t += 2) {
    step(t, pr0, hb_[0], hb_[1]);
    step(t + 1, pr1, hb_[1], hb_[0]);
  }
}

// ---------------- persistent 4-stage pipeline ----------------
// One launch. Blocks: 0-3 rec0[pair], 4-7 proj1[pair], 8-11 rec1[pair],
// 12-43 proj0[2 batches each]. Chunk-granularity release/acquire flags
// (agent scope) carry cross-XCD coherence (G16). Gate DAG (monotone, no
// cycle): rec0(c) <- {proj0_cnt>=32*min(c+2,C), proj1[p]>=c-1 (2-slot ring
// backpressure; also guards proj1 overwriting pre0 region)};
// proj1(ch) <- rec0[p]>=ch+1; rec1(ch) <- proj1[p]>=ch+1.
// W fragments load once; h carries persist in LDS across chunks.
__global__ __launch_bounds__(512, 1) void persist_k(
    const float* X, float* dout,
    const float* Wih0, const float* bih0, const float* bhh0, const float* Whh0,
    const float* Wih1, const float* Whh1, const float* bih1, const float* bhh1,
    u16* ring, u32* flags) {
  __shared__ __align__(16) char smem[2 * 8192];
  const int tid = threadIdx.x;
  const int lane = tid & 63, wv = tid >> 6;
  const int bl = lane & 15, g = lane >> 4;
  const int bid = blockIdx.x;
  char* sb0 = smem;
  char* sb1 = smem + 8192;
  u32* proj0_cnt = flags;                       // 128B-strided flags
  auto rec0_prog = [&](int p) { return flags + 32 + 32 * p; };
  auto proj1_prog = [&](int p) { return flags + 160 + 32 * p; };

  if (bid < 4) {
    // ---------- rec0[pair p]: layer-0 recurrence, chunks 0..C-1 ----------
    const int p = bid;
    uint4 wf[2][8];
    load_wfrag<2>(Whh0, wv * 2, bl, g, wf);
    { uint4 z = make_uint4(0, 0, 0, 0); ((uint4*)sb0)[tid] = z; }
    __syncthreads();
    const float* prow = dout + (size_t)(p * 16 + bl) * T_ * H_;
    u16* rb = ring + (size_t)(p * 16 + bl) * H_;

    for (int c = 0; c < C_; ++c) {
      const u32 ptgt = 32u * (u32)((c + 2 < C_) ? (c + 2) : C_);
      wait_ge(proj0_cnt, ptgt);                    // pre0 ready (incl. overhang)
      if (c >= 1) wait_ge(proj1_prog(p), (u32)(c - 1));  // ring backpressure
      const float* pch = prow + (size_t)c * S_ * H_;
      u16* rch = rb + ((size_t)(c & 1) * S_) * (B_ * H_);
      float4 pr0[2], pr1[2];
#pragma unroll
      for (int q = 0; q < 2; ++q) {
        const int j0 = (wv * 2 + q) * 16 + g * 4;
        pr0[q] = *(const float4*)(pch + 0 * H_ + j0);
        pr1[q] = *(const float4*)(pch + 1 * H_ + j0);
      }
      auto step = [&](int s, float4 (&pr)[2], char* rbuf, char* wbuf) {
        uint4 hf[8];
#pragma unroll
        for (int kc = 0; kc < 8; ++kc)
          hf[kc] = *(const uint4*)(rbuf + SWZ(bl, kc * 64 + g * 16));
        f32x4 accA[2], accB[2];
#pragma unroll
        for (int q = 0; q < 2; ++q) {
          accA[q] = (f32x4){0.f, 0.f, 0.f, 0.f};
          accB[q] = (f32x4){0.f, 0.f, 0.f, 0.f};
#pragma unroll
          for (int kc = 0; kc < 4; ++kc) {
            accA[q] = mfma4(wf[q][kc], hf[kc], accA[q]);
            accB[q] = mfma4(wf[q][kc + 4], hf[kc + 4], accB[q]);
          }
        }
#pragma unroll
        for (int q = 0; q < 2; ++q) {
          const int j0 = (wv * 2 + q) * 16 + g * 4;
          const float* pq = (const float*)&pr[q];
          float v0 = fast_tanh(accA[q][0] + accB[q][0] + pq[0]);
          float v1 = fast_tanh(accA[q][1] + accB[q][1] + pq[1]);
          float v2 = fast_tanh(accA[q][2] + accB[q][2] + pq[2]);
          float v3 = fast_tanh(accA[q][3] + accB[q][3] + pq[3]);
          uint2 hw; hw.x = cvtpk(v0, v1); hw.y = cvtpk(v2, v3);
          *(uint2*)(wbuf + SWZ(bl, j0 * 2)) = hw;            // h0 for s+1
          *(uint2*)(rch + (size_t)s * (B_ * H_) + j0) = hw;  // h0 -> ring
          if (s + 2 < S_)
            pr[q] = *(const float4*)(pch + (size_t)(s + 2) * H_ + j0);
        }
        asm volatile("s_waitcnt lgkmcnt(0)" ::: "memory");
        __builtin_amdgcn_s_barrier();
        __builtin_amdgcn_sched_barrier(0);
      };
      for (int s = 0; s < S_; s += 2) {
        step(s, pr0, sb0, sb1);
        step(s + 1, pr1, sb1, sb0);
      }
      publish_val(rec0_prog(p), (u32)(c + 1));
    }
  } else if (bid < 8) {
    // ---------- proj1[pair p]: c1 = Wih1.h0 + b -> f32 into d_out ----------
    const int p = bid - 4;
    uint4 wf[2][8];
    load_wfrag<2>(Wih1, wv * 2, bl, g, wf);
    float4 cb[2];
#pragma unroll
    for (int q = 0; q < 2; ++q) {
      const int j0 = (wv * 2 + q) * 16 + g * 4;
      float4 a = *(const float4*)(bih1 + j0);
      float4 b = *(const float4*)(bhh1 + j0);
      cb[q].x = a.x + b.x; cb[q].y = a.y + b.y;
      cb[q].z = a.z + b.z; cb[q].w = a.w + b.w;
    }
    const int sr = tid >> 5, scb = (tid & 31) * 16;
    for (int ch = 0; ch < C_; ++ch) {
      wait_ge(rec0_prog(p), (u32)(ch + 1));  // ring slot complete + pre0 consumed
      const u16* rbase2 = ring + ((size_t)(ch & 1) * S_) * (B_ * H_) + (size_t)p * 16 * H_;
      uint4 v = *(const uint4*)(rbase2 + (size_t)sr * H_ + (tid & 31) * 8);
      for (int s = 0; s < S_; ++s) {
        char* sb = (s & 1) ? sb1 : sb0;
        *(uint4*)(sb + SWZ(sr, scb)) = v;
        __syncthreads();
        if (s + 1 < S_)
          v = *(const uint4*)(rbase2 + (size_t)(s + 1) * (B_ * H_) + (size_t)sr * H_ + (tid & 31) * 8);
        uint4 hf[8];
#pragma unroll
        for (int kc = 0; kc < 8; ++kc)
          hf[kc] = *(const uint4*)(sb + SWZ(bl, kc * 64 + g * 16));
        f32x4 acc[2];
#pragma unroll
        for (int q = 0; q < 2; ++q) {
          acc[q] = (f32x4){0.f, 0.f, 0.f, 0.f};
#pragma unroll
          for (int kc = 0; kc < 8; ++kc)
            acc[q] = mfma4(wf[q][kc], hf[kc], acc[q]);
        }
        float* od = dout + (size_t)(p * 16 + bl) * T_ * H_ + (size_t)(ch * S_ + s) * H_;
#pragma unroll
        for (int q = 0; q < 2; ++q) {
          const int j0 = (wv * 2 + q) * 16 + g * 4;
          float4 o;
          o.x = acc[q][0] + cb[q].x; o.y = acc[q][1] + cb[q].y;
          o.z = acc[q][2] + cb[q].z; o.w = acc[q][3] + cb[q].w;
          *(float4*)(od + j0) = o;
        }
        __syncthreads();
      }
      publish_val(proj1_prog(p), (u32)(ch + 1));
    }
  } else if (bid < 12) {
    // ---------- rec1[pair p]: layer-1 recurrence, in-place on d_out ----------
    const int p = bid - 8;
    uint4 wf[2][8];
    load_wfrag<2>(Whh1, wv * 2, bl, g, wf);
    { uint4 z = make_uint4(0, 0, 0, 0); ((uint4*)sb0)[tid] = z; }
    __syncthreads();
    float* prow = dout + (size_t)(p * 16 + bl) * T_ * H_;

    for (int ch = 0; ch < C_; ++ch) {
      wait_ge(proj1_prog(p), (u32)(ch + 1));  // c1 chunk ready
      float* pch = prow + (size_t)ch * S_ * H_;
      float4 pr0[2], pr1[2];
#pragma unroll
      for (int q = 0; q < 2; ++q) {
        const int j0 = (wv * 2 + q) * 16 + g * 4;
        pr0[q] = *(const float4*)(pch + 0 * H_ + j0);
        pr1[q] = *(const float4*)(pch + 1 * H_ + j0);
      }
      auto step = [&](int s, float4 (&pr)[2], char* rbuf, char* wbuf) {
        uint4 hf[8];
#pragma unroll
        for (int kc = 0; kc < 8; ++kc)
          hf[kc] = *(const uint4*)(rbuf + SWZ(bl, kc * 64 + g * 16));
        f32x4 accA[2], accB[2];
#pragma unroll
        for (int q = 0; q < 2; ++q) {
          accA[q] = (f32x4){0.f, 0.f, 0.f, 0.f};
          accB[q] = (f32x4){0.f, 0.f, 0.f, 0.f};
#pragma unroll
          for (int kc = 0; kc < 4; ++kc) {
            accA[q] = mfma4(wf[q][kc], hf[kc], accA[q]);
            accB[q] = mfma4(wf[q][kc + 4], hf[kc + 4], accB[q]);
          }
        }
#pragma unroll
        for (int q = 0; q < 2; ++q) {
          const int j0 = (wv * 2 + q) * 16 + g * 4;
          const float* pq = (const float*)&pr[q];
          float v0 = fast_tanh(accA[q][0] + accB[q][0] + pq[0]);
          float v1 = fast_tanh(accA[q][1] + accB[q][1] + pq[1]);
          float v2 = fast_tanh(accA[q][2] + accB[q][2] + pq[2]);
          float v3 = fast_tanh(accA[q][3] + accB[q][3] + pq[3]);
          uint2 hw; hw.x = cvtpk(v0, v1); hw.y = cvtpk(v2, v3);
          *(uint2*)(wbuf + SWZ(bl, j0 * 2)) = hw;         // h1 for s+1
          float4 o; o.x = v0; o.y = v1; o.z = v2; o.w = v3;
          *(float4*)(pch + (size_t)s * H_ + j0) = o;      // in-place final out
          if (s + 2 < S_)
            pr[q] = *(const float4*)(pch + (size_t)(s + 2) * H_ + j0);
        }
        asm volatile("s_waitcnt lgkmcnt(0)" ::: "memory");
        __builtin_amdgcn_s_barrier();
        __builtin_amdgcn_sched_barrier(0);
      };
      for (int s = 0; s < S_; s += 2) {
        step(s, pr0, sb0, sb1);
        step(s + 1, pr1, sb1, sb0);
      }
      // no flag: nothing downstream of rec1
    }
  } else {
    // ---------- proj0[b2]: pre0 chunks 0..C-1, free-running ----------
    const int b2 = bid - 12;
    uint4 wf[2][8];
    load_wfrag<2>(Wih0, wv * 2, bl, g, wf);
    float4 cb[2];
#pragma unroll
    for (int q = 0; q < 2; ++q) {
      const int j0 = (wv * 2 + q) * 16 + g * 4;
      float4 a = *(const float4*)(bih0 + j0);
      float4 b = *(const float4*)(bhh0 + j0);
      cb[q].x = a.x + b.x; cb[q].y = a.y + b.y;
      cb[q].z = a.z + b.z; cb[q].w = a.w + b.w;
    }
    for (int c = 0; c < C_; ++c) {
      proj0_body(smem, X, Wih0, bih0, bhh0, dout, c, b2, wf, cb);
      publish_add(proj0_cnt);
    }
  }
}

extern "C" void kernel_launch(void* const* d_in, const int* in_sizes, int n_in,
                              void* d_out, int out_size, void* d_ws, size_t ws_size,
                              hipStream_t stream) {
  (void)in_sizes; (void)n_in; (void)out_size;
  const float* x    = (const float*)d_in[0];
  const float* Wih0 = (const float*)d_in[1];
  const float* Whh0 = (const float*)d_in[2];
  const float* bih0 = (const float*)d_in[3];
  const float* bhh0 = (const float*)d_in[4];
  const float* Wih1 = (const float*)d_in[5];
  const float* Whh1 = (const float*)d_in[6];
  const float* bih1 = (const float*)d_in[7];
  const float* bhh1 = (const float*)d_in[8];
  float* out = (float*)d_out;

  const size_t ring_bytes = (size_t)2 * S_ * B_ * H_ * sizeof(u16);  // 4.19 MB
  const size_t need = 4096 + ring_bytes;

  if (ws_size >= need) {
    u32* flags = (u32*)d_ws;
    u16* ring = (u16*)((char*)d_ws + 4096);
    init_flags<<<dim3(1), dim3(1024), 0, stream>>>(flags);
    persist_k<<<dim3(44), dim3(512), 0, stream>>>(
        x, out, Wih0, bih0, bhh0, Whh0, Wih1, Whh1, bih1, bhh1, ring, flags);
  } else {  // fallback: verified round-6 sequence
    const int TPW = 8;
    const int NWG = (B_ * T_) / (TPW * 16);  // 1024
    pre_mfma<<<dim3(NWG), dim3(256), 0, stream>>>(x, Wih0, bih0, bhh0, out, TPW);
    rec_mfma<<<dim3(B_ / 16), dim3(512), 0, stream>>>(out, Whh0, out);
    pre_mfma<<<dim3(NWG), dim3(256), 0, stream>>>(out, Wih1, bih1, bhh1, out, TPW);
    rec_mfma<<<dim3(B_ / 16), dim3(512), 0, stream>>>(out, Whh1, out);
  }
}